// Round 1
// baseline (283.293 us; speedup 1.0000x reference)
//
#include <hip/hip_runtime.h>

#define NN 16384
#define CC 64
#define BB 32

typedef __attribute__((ext_vector_type(8))) short bf16x8;
typedef __attribute__((ext_vector_type(4))) float f32x4;
typedef __attribute__((ext_vector_type(16))) float f32x16;

__device__ __forceinline__ unsigned short f2bf(float f) {
    // round-to-nearest-even fp32 -> bf16 (inputs are normal floats)
    unsigned int u = __float_as_uint(f);
    unsigned int r = (u + 0x7fffu + ((u >> 16) & 1u)) >> 16;
    return (unsigned short)r;
}

__device__ __forceinline__ bf16x8 cvt8(float4 a, float4 b) {
    union { bf16x8 v; unsigned short s[8]; } u;
    u.s[0] = f2bf(a.x); u.s[1] = f2bf(a.y); u.s[2] = f2bf(a.z); u.s[3] = f2bf(a.w);
    u.s[4] = f2bf(b.x); u.s[5] = f2bf(b.y); u.s[6] = f2bf(b.z); u.s[7] = f2bf(b.w);
    return u.v;
}

// ---------------- K1: spectral norm, Wsn = W / sigma ----------------
__global__ __launch_bounds__(64) void k_sigma(const float* __restrict__ W,
                                              const float* __restrict__ u,
                                              float* __restrict__ Wsn) {
    __shared__ float sv[64];
    int c = threadIdx.x; // one wave of 64
    // t = W^T @ u
    float t = 0.f;
    for (int r = 0; r < 64; ++r) t += W[r * 64 + c] * u[r];
    float s = t * t;
    #pragma unroll
    for (int m = 1; m < 64; m <<= 1) s += __shfl_xor(s, m);
    float nv = sqrtf(s);
    float v = t / fmaxf(nv, 1e-12f);
    sv[c] = v;
    __syncthreads();
    // wv = W @ v
    float wv = 0.f;
    for (int k = 0; k < 64; ++k) wv += W[c * 64 + k] * sv[k];
    float s2 = wv * wv;
    #pragma unroll
    for (int m = 1; m < 64; m <<= 1) s2 += __shfl_xor(s2, m);
    float nw = sqrtf(s2);
    // sigma = u2 . wv where u2 = wv / max(nw, eps)  =>  s2 / max(nw, eps)
    float sigma = s2 / fmaxf(nw, 1e-12f);
    float inv = 1.0f / fmaxf(sigma, 1e-30f);
    for (int i = c; i < 4096; i += 64) Wsn[i] = W[i] * inv;
}

// ---------------- K2: per-batch Gram G_b = X_b X_b^T (bf16 MFMA) ----------------
// grid = BB * S blocks, 256 threads (4 waves). Each wave: full 64x64 Gram over 256 cols.
__global__ __launch_bounds__(256) void k_gram(const float* __restrict__ x,
                                              float* __restrict__ G) {
    const int S = 16;
    int b = blockIdx.x / S, chunk = blockIdx.x % S;
    int wave = threadIdx.x >> 6, lane = threadIdx.x & 63;
    int lrow = lane & 15, quad = lane >> 4;
    const float* xb = x + (size_t)b * CC * NN;
    int kbase = chunk * (NN / S) + wave * (NN / S / 4); // 1024 per chunk, 256 per wave

    f32x4 acc[4][4] = {};
    for (int ks = 0; ks < 8; ++ks) {
        int k0 = kbase + ks * 32 + quad * 8;
        bf16x8 fr[4];
        #pragma unroll
        for (int ti = 0; ti < 4; ++ti) {
            const float* p = xb + (size_t)(16 * ti + lrow) * NN + k0;
            float4 a  = *(const float4*)p;
            float4 b4 = *(const float4*)(p + 4);
            fr[ti] = cvt8(a, b4);
        }
        #pragma unroll
        for (int mi = 0; mi < 4; ++mi)
            #pragma unroll
            for (int ni = 0; ni < 4; ++ni)
                acc[mi][ni] = __builtin_amdgcn_mfma_f32_16x16x32_bf16(
                    fr[mi], fr[ni], acc[mi][ni], 0, 0, 0);
    }

    // block-level reduction of the 4 waves' partial Grams
    __shared__ float Gs[4096];
    for (int w = 0; w < 4; ++w) {
        if (wave == w) {
            #pragma unroll
            for (int mi = 0; mi < 4; ++mi)
                #pragma unroll
                for (int ni = 0; ni < 4; ++ni)
                    #pragma unroll
                    for (int r = 0; r < 4; ++r) {
                        int row = 16 * mi + quad * 4 + r;  // D row = quad*4 + reg
                        int col = 16 * ni + lrow;          // D col = lane&15
                        if (w == 0) Gs[row * 64 + col]  = acc[mi][ni][r];
                        else        Gs[row * 64 + col] += acc[mi][ni][r];
                    }
        }
        __syncthreads();
    }
    float* Gb = G + b * 4096;
    for (int i = threadIdx.x; i < 4096; i += 256) atomicAdd(&Gb[i], Gs[i]);
}

// ---------------- K3: A_b = gamma * G_b @ Wsn + I, emit bf16 A-fragments ----------------
// Fragment order for mfma_f32_32x32x16_bf16 A-operand:
//   value(ks,mi,lane,j) = A[32*mi + (lane&31)][ks*16 + (lane>>5)*8 + j]
__global__ __launch_bounds__(256) void k_build_A(const float* __restrict__ G,
                                                 const float* __restrict__ Wsn,
                                                 const float* __restrict__ gamma,
                                                 unsigned short* __restrict__ Afrag) {
    int b = blockIdx.x;
    __shared__ float Gs[4096], Ws[4096], As[4096];
    for (int i = threadIdx.x; i < 4096; i += 256) {
        Gs[i] = G[b * 4096 + i];
        Ws[i] = Wsn[i];
    }
    __syncthreads();
    float g = gamma[0];
    for (int i = threadIdx.x; i < 4096; i += 256) {
        int r = i >> 6, c = i & 63;
        float a = 0.f;
        #pragma unroll 8
        for (int k = 0; k < 64; ++k) a += Gs[r * 64 + k] * Ws[k * 64 + c];
        a *= g;
        if (r == c) a += 1.f;
        As[i] = a;
    }
    __syncthreads();
    unsigned short* Ab = Afrag + b * 4096;
    for (int fi = threadIdx.x; fi < 4096; fi += 256) {
        int j = fi & 7, lane = (fi >> 3) & 63, mi = (fi >> 9) & 1, ks = fi >> 10;
        int row = 32 * mi + (lane & 31);
        int col = ks * 16 + (lane >> 5) * 8 + j;
        Ab[fi] = f2bf(As[row * 64 + col]);
    }
}

// ---------------- K4: out_b = A_b @ X_b (bf16 MFMA 32x32x16) ----------------
// grid = BB * 128 blocks, 256 threads (4 waves). Block tile: 64 rows x 128 cols.
#define PITCH 72  // bf16 elems per LDS row (144 B, 16B-multiple for aligned b128 reads)
__global__ __launch_bounds__(256) void k_out(const float* __restrict__ x,
                                             const unsigned short* __restrict__ Afrag,
                                             float* __restrict__ out) {
    int nblk = blockIdx.x & 127;
    int b = blockIdx.x >> 7;
    int col0 = nblk * 128;
    int wave = threadIdx.x >> 6, lane = threadIdx.x & 63;
    const float* xb = x + (size_t)b * CC * NN;

    __shared__ unsigned short XT[128 * PITCH]; // transposed tile: [n][k]

    // stage + transpose: thread handles row pair (2p, 2p+1), 16 cols; packs 2 k's per 4B write
    {
        int p  = threadIdx.x >> 3;        // 0..31  -> rows 2p, 2p+1
        int cs = (threadIdx.x & 7) * 16;  // 0..112
        int r0 = p * 2;
        const float* pr0 = xb + (size_t)r0 * NN + col0 + cs;
        const float* pr1 = pr0 + NN;
        #pragma unroll
        for (int q = 0; q < 4; ++q) {
            float4 a  = *(const float4*)(pr0 + q * 4);
            float4 b4 = *(const float4*)(pr1 + q * 4);
            const float* av = (const float*)&a;
            const float* bv = (const float*)&b4;
            #pragma unroll
            for (int e = 0; e < 4; ++e) {
                int n = cs + q * 4 + e;
                unsigned int lo = f2bf(av[e]);
                unsigned int hi = f2bf(bv[e]);
                *(unsigned int*)&XT[n * PITCH + r0] = lo | (hi << 16);
            }
        }
    }

    // A fragments (pre-swizzled by K3): 4 k-steps x 2 m-tiles
    bf16x8 af[4][2];
    const unsigned short* Ab = Afrag + (size_t)b * 4096;
    #pragma unroll
    for (int ks = 0; ks < 4; ++ks)
        #pragma unroll
        for (int mi = 0; mi < 2; ++mi)
            af[ks][mi] = *(const bf16x8*)(Ab + ((ks * 2 + mi) * 64 + lane) * 8);

    __syncthreads();

    f32x16 acc[2] = {};
    int n = wave * 32 + (lane & 31);
    int khalf = (lane >> 5) * 8;
    #pragma unroll
    for (int ks = 0; ks < 4; ++ks) {
        bf16x8 bf = *(const bf16x8*)&XT[n * PITCH + ks * 16 + khalf];
        acc[0] = __builtin_amdgcn_mfma_f32_32x32x16_bf16(af[ks][0], bf, acc[0], 0, 0, 0);
        acc[1] = __builtin_amdgcn_mfma_f32_32x32x16_bf16(af[ks][1], bf, acc[1], 0, 0, 0);
    }

    // store: D col = lane&31, row = (reg&3) + 8*(reg>>2) + 4*(lane>>5)
    float* ob = out + (size_t)b * CC * NN;
    int gcol = col0 + n;
    #pragma unroll
    for (int mi = 0; mi < 2; ++mi)
        #pragma unroll
        for (int r = 0; r < 16; ++r) {
            int grow = 32 * mi + (r & 3) + 8 * (r >> 2) + 4 * (lane >> 5);
            ob[(size_t)grow * NN + gcol] = acc[mi][r];
        }
}

extern "C" void kernel_launch(void* const* d_in, const int* in_sizes, int n_in,
                              void* d_out, int out_size, void* d_ws, size_t ws_size,
                              hipStream_t stream) {
    const float* x     = (const float*)d_in[0];
    const float* W     = (const float*)d_in[1];
    const float* gamma = (const float*)d_in[2];
    const float* u     = (const float*)d_in[3];
    float* out = (float*)d_out;

    char* ws = (char*)d_ws;
    float* Wsn            = (float*)ws;                              // 16 KB
    float* G              = (float*)(ws + 16 * 1024);                // 512 KB
    unsigned short* Afrag = (unsigned short*)(ws + 528 * 1024);      // 256 KB

    hipMemsetAsync(G, 0, (size_t)BB * 4096 * sizeof(float), stream);
    k_sigma<<<1, 64, 0, stream>>>(W, u, Wsn);
    k_gram<<<BB * 16, 256, 0, stream>>>(x, G);
    k_build_A<<<BB, 256, 0, stream>>>(G, Wsn, gamma, Afrag);
    k_out<<<BB * 128, 256, 0, stream>>>(x, Afrag, out);
}

// Round 2
// 278.532 us; speedup vs baseline: 1.0171x; 1.0171x over previous
//
#include <hip/hip_runtime.h>

#define NN 16384
#define CC 64
#define BB 32

typedef __attribute__((ext_vector_type(8))) short bf16x8;
typedef __attribute__((ext_vector_type(4))) short bf16x4;
typedef __attribute__((ext_vector_type(4))) float f32x4;
typedef __attribute__((ext_vector_type(16))) float f32x16;

__device__ __forceinline__ unsigned short f2bf(float f) {
    unsigned int u = __float_as_uint(f);
    unsigned int r = (u + 0x7fffu + ((u >> 16) & 1u)) >> 16;
    return (unsigned short)r;
}

__device__ __forceinline__ bf16x8 cvt8(float4 a, float4 b) {
    union { bf16x8 v; unsigned short s[8]; } u;
    u.s[0] = f2bf(a.x); u.s[1] = f2bf(a.y); u.s[2] = f2bf(a.z); u.s[3] = f2bf(a.w);
    u.s[4] = f2bf(b.x); u.s[5] = f2bf(b.y); u.s[6] = f2bf(b.z); u.s[7] = f2bf(b.w);
    return u.v;
}

// ---------------- K1: per-batch Gram partials, no atomics ----------------
// grid = BB*8 blocks, 512 threads (8 waves). Block (b,chunk): cols chunk*2048..+2048,
// wave w covers 256 cols. Per-wave LDS partial (64x68 padded), parallel reduce,
// coalesced store to Gp[b][chunk][4096].
#define GP 68  // float pitch: bank stride (4*GP/4)%32 = 4 -> scattered writes 2-way = free
__global__ __launch_bounds__(512) void k_gram(const float* __restrict__ x,
                                              float* __restrict__ Gp) {
    int b = blockIdx.x >> 3, chunk = blockIdx.x & 7;
    int wave = threadIdx.x >> 6, lane = threadIdx.x & 63;
    int lrow = lane & 15, quad = lane >> 4;
    const float* xb = x + (size_t)b * CC * NN;
    int kbase = chunk * 2048 + wave * 256;

    __shared__ float Gw[8 * 64 * GP];  // 139264 B

    f32x4 acc[4][4] = {};
    for (int ks = 0; ks < 8; ++ks) {
        int k0 = kbase + ks * 32 + quad * 8;
        bf16x8 fr[4];
        #pragma unroll
        for (int ti = 0; ti < 4; ++ti) {
            const float* p = xb + (size_t)(16 * ti + lrow) * NN + k0;
            float4 a  = *(const float4*)p;
            float4 b4 = *(const float4*)(p + 4);
            fr[ti] = cvt8(a, b4);
        }
        #pragma unroll
        for (int mi = 0; mi < 4; ++mi)
            #pragma unroll
            for (int ni = 0; ni < 4; ++ni)
                acc[mi][ni] = __builtin_amdgcn_mfma_f32_16x16x32_bf16(
                    fr[mi], fr[ni], acc[mi][ni], 0, 0, 0);
    }

    float* gw = Gw + wave * 64 * GP;
    #pragma unroll
    for (int mi = 0; mi < 4; ++mi)
        #pragma unroll
        for (int ni = 0; ni < 4; ++ni)
            #pragma unroll
            for (int r = 0; r < 4; ++r) {
                int row = 16 * mi + quad * 4 + r;
                int col = 16 * ni + lrow;
                gw[row * GP + col] = acc[mi][ni][r];
            }
    __syncthreads();

    float* gp = Gp + ((size_t)b * 8 + chunk) * 4096;
    for (int i = threadIdx.x; i < 4096; i += 512) {
        int off = (i >> 6) * GP + (i & 63);
        float s = 0.f;
        #pragma unroll
        for (int w = 0; w < 8; ++w) s += Gw[w * 64 * GP + off];
        gp[i] = s;
    }
}

// ---------------- K2: fused sigma + G-reduce + A = (gamma/sigma)*G@W + I ----------------
// grid = BB blocks, 256 threads. Emits bf16 A-fragments pre-swizzled for
// mfma_f32_32x32x16_bf16 A-operand: value(ks,mi,lane,j) = A[32mi+(lane&31)][16ks+(lane>>5)*8+j]
__global__ __launch_bounds__(256) void k_build_A(const float* __restrict__ W,
                                                 const float* __restrict__ u,
                                                 const float* __restrict__ gamma,
                                                 const float* __restrict__ Gp,
                                                 unsigned short* __restrict__ Afrag) {
    int b = blockIdx.x;
    int tid = threadIdx.x;
    __shared__ float Ws[4096];
    __shared__ float Gs[64 * 65];
    __shared__ float As[64 * 68];
    __shared__ float us[64];
    __shared__ float gshare;

    for (int i = tid; i < 4096; i += 256) Ws[i] = W[i];
    if (tid < 64) us[tid] = u[tid];
    __syncthreads();

    // wave 0: spectral norm (one power iteration), fold 1/sigma into gamma
    if (tid < 64) {
        int c = tid;
        float t = 0.f;
        #pragma unroll 8
        for (int r = 0; r < 64; ++r) t += Ws[r * 64 + c] * us[r];
        float s = t * t;
        #pragma unroll
        for (int m = 1; m < 64; m <<= 1) s += __shfl_xor(s, m);
        float v = t / fmaxf(sqrtf(s), 1e-12f);
        float wv = 0.f;
        #pragma unroll 8
        for (int k = 0; k < 64; ++k) wv += Ws[c * 64 + k] * __shfl(v, k);
        float s2 = wv * wv;
        #pragma unroll
        for (int m = 1; m < 64; m <<= 1) s2 += __shfl_xor(s2, m);
        float nw = sqrtf(s2);
        float sigma = s2 / fmaxf(nw, 1e-12f);
        if (c == 0) gshare = gamma[0] / fmaxf(sigma, 1e-30f);
    }

    // all threads: reduce the 8 Gram partials (coalesced)
    const float* gp = Gp + (size_t)b * 8 * 4096;
    for (int i = tid; i < 4096; i += 256) {
        float s = 0.f;
        #pragma unroll
        for (int c = 0; c < 8; ++c) s += gp[c * 4096 + i];
        Gs[(i >> 6) * 65 + (i & 63)] = s;
    }
    __syncthreads();

    // A[r][c] = g2 * sum_k G[r][k] W[k][c] + (r==c)
    {
        int r = tid >> 2, j0 = (tid & 3) * 16;
        float a[16];
        #pragma unroll
        for (int j = 0; j < 16; ++j) a[j] = 0.f;
        for (int k = 0; k < 64; ++k) {
            float g = Gs[r * 65 + k];
            const float* wr = &Ws[k * 64 + j0];
            float4 w0 = *(const float4*)(wr);
            float4 w1 = *(const float4*)(wr + 4);
            float4 w2 = *(const float4*)(wr + 8);
            float4 w3 = *(const float4*)(wr + 12);
            a[0]  += g * w0.x; a[1]  += g * w0.y; a[2]  += g * w0.z; a[3]  += g * w0.w;
            a[4]  += g * w1.x; a[5]  += g * w1.y; a[6]  += g * w1.z; a[7]  += g * w1.w;
            a[8]  += g * w2.x; a[9]  += g * w2.y; a[10] += g * w2.z; a[11] += g * w2.w;
            a[12] += g * w3.x; a[13] += g * w3.y; a[14] += g * w3.z; a[15] += g * w3.w;
        }
        float g2 = gshare;
        #pragma unroll
        for (int j = 0; j < 16; ++j) {
            float vv = a[j] * g2 + ((r == j0 + j) ? 1.f : 0.f);
            As[r * 68 + j0 + j] = vv;
        }
    }
    __syncthreads();

    // emit pre-swizzled bf16 fragments
    unsigned short* Ab = Afrag + (size_t)b * 4096;
    for (int fv = tid; fv < 512; fv += 256) {
        int ks = fv >> 7, mi = (fv >> 6) & 1, lane = fv & 63;
        int row = 32 * mi + (lane & 31);
        int col = 16 * ks + (lane >> 5) * 8;
        float4 a4 = *(const float4*)&As[row * 68 + col];
        float4 b4 = *(const float4*)&As[row * 68 + col + 4];
        *(bf16x8*)(Ab + (size_t)fv * 8) = cvt8(a4, b4);
    }
}

// ---------------- K3: out_b = A_b @ X_b (bf16 MFMA 32x32x16) ----------------
// grid = BB*128 blocks, 256 threads (4 waves). Block tile: 64 rows x 128 cols.
#define PITCH 68  // shorts per XT row; write banks (2n+rp)%32 conflict-free, b64 reads balanced
__global__ __launch_bounds__(256) void k_out(const float* __restrict__ x,
                                             const unsigned short* __restrict__ Afrag,
                                             float* __restrict__ out) {
    int nblk = blockIdx.x & 127;
    int b = blockIdx.x >> 7;
    int col0 = nblk * 128;
    int wave = threadIdx.x >> 6, lane = threadIdx.x & 63;
    const float* xb = x + (size_t)b * CC * NN;

    __shared__ __align__(16) unsigned short XT[128 * PITCH]; // transposed tile [n][k]

    // stage + transpose: rp = row pair (0..31), nc = 16-col chunk (0..7)
    {
        int rp = threadIdx.x & 31;
        int nc = threadIdx.x >> 5;
        int r0 = rp * 2;
        int cs = nc * 16;
        const float* pr0 = xb + (size_t)r0 * NN + col0 + cs;
        const float* pr1 = pr0 + NN;
        #pragma unroll
        for (int q = 0; q < 4; ++q) {
            float4 a  = *(const float4*)(pr0 + q * 4);
            float4 b4 = *(const float4*)(pr1 + q * 4);
            const float* av = (const float*)&a;
            const float* bv = (const float*)&b4;
            #pragma unroll
            for (int e = 0; e < 4; ++e) {
                int n = cs + q * 4 + e;
                unsigned int lo = f2bf(av[e]);
                unsigned int hi = f2bf(bv[e]);
                *(unsigned int*)&XT[n * PITCH + r0] = lo | (hi << 16);
            }
        }
    }

    // A fragments (pre-swizzled): 4 k-steps x 2 m-tiles
    bf16x8 af[4][2];
    const unsigned short* Ab = Afrag + (size_t)b * 4096;
    #pragma unroll
    for (int ks = 0; ks < 4; ++ks)
        #pragma unroll
        for (int mi = 0; mi < 2; ++mi)
            af[ks][mi] = *(const bf16x8*)(Ab + ((ks * 2 + mi) * 64 + lane) * 8);

    __syncthreads();

    f32x16 acc[2] = {};
    int n = wave * 32 + (lane & 31);
    int kh = (lane >> 5) * 8;
    #pragma unroll
    for (int ks = 0; ks < 4; ++ks) {
        union { bf16x8 v; bf16x4 h[2]; } bu;
        bu.h[0] = *(const bf16x4*)&XT[n * PITCH + ks * 16 + kh];
        bu.h[1] = *(const bf16x4*)&XT[n * PITCH + ks * 16 + kh + 4];
        acc[0] = __builtin_amdgcn_mfma_f32_32x32x16_bf16(af[ks][0], bu.v, acc[0], 0, 0, 0);
        acc[1] = __builtin_amdgcn_mfma_f32_32x32x16_bf16(af[ks][1], bu.v, acc[1], 0, 0, 0);
    }

    // store: D col = lane&31, row = (reg&3) + 8*(reg>>2) + 4*(lane>>5)
    float* ob = out + (size_t)b * CC * NN;
    int gcol = col0 + n;
    #pragma unroll
    for (int mi = 0; mi < 2; ++mi)
        #pragma unroll
        for (int r = 0; r < 16; ++r) {
            int grow = 32 * mi + (r & 3) + 8 * (r >> 2) + 4 * (lane >> 5);
            ob[(size_t)grow * NN + gcol] = acc[mi][r];
        }
}

extern "C" void kernel_launch(void* const* d_in, const int* in_sizes, int n_in,
                              void* d_out, int out_size, void* d_ws, size_t ws_size,
                              hipStream_t stream) {
    const float* x     = (const float*)d_in[0];
    const float* W     = (const float*)d_in[1];
    const float* gamma = (const float*)d_in[2];
    const float* u     = (const float*)d_in[3];
    float* out = (float*)d_out;

    char* ws = (char*)d_ws;
    float* Gp             = (float*)ws;                         // 32*8*4096*4 = 4 MB
    unsigned short* Afrag = (unsigned short*)(ws + (5 << 20));  // 256 KB

    k_gram<<<BB * 8, 512, 0, stream>>>(x, Gp);
    k_build_A<<<BB, 256, 0, stream>>>(W, u, gamma, Gp, Afrag);
    k_out<<<BB * 128, 256, 0, stream>>>(x, Afrag, out);
}